// Round 8
// baseline (262.939 us; speedup 1.0000x reference)
//
#include <hip/hip_runtime.h>
#include <math.h>

typedef __attribute__((ext_vector_type(8))) short short8;
typedef __attribute__((ext_vector_type(4))) float float4v;
typedef __attribute__((ext_vector_type(4))) int   int4v;
typedef unsigned int uint;

#define BATCH 8
#define SEQ   4096
#define DIM   768
#define HID   512
#define M_TOK (BATCH * SEQ)   // 32768

// ---------- helpers ----------
static __device__ __forceinline__ short f2bf_rne(float x) {
    unsigned int u = __float_as_uint(x);
    unsigned int r = (u + 0x7FFFu + ((u >> 16) & 1u)) >> 16;   // RNE
    return (short)r;
}
// pack two floats -> 2 bf16 (truncate) in ONE v_perm_b32. lo=bf16(a), hi=bf16(b).
static __device__ __forceinline__ uint pack_bf2(float a, float b) {
    return __builtin_amdgcn_perm(__float_as_uint(b), __float_as_uint(a), 0x07060302u);
}
union FragU { uint u[4]; short8 s; int4v i4; };
// async global->LDS DMA, 16 B per lane; lds dest = uniform base + lane*16,
// global src is PER-LANE.
static __device__ __forceinline__ void gl2lds16(const void* g, void* l) {
    __builtin_amdgcn_global_load_lds(
        (const __attribute__((address_space(1))) unsigned int*)g,
        (__attribute__((address_space(3))) unsigned int*)l, 16, 0, 0);
}

// ---------- prep: W1 [DIM][HID] fp32 -> W1T in B-FRAGMENT-LINEAR bf16 chunks.
// Chunk id = h*24 + kg  (h = n/16 in 0..31, kg = k/32 in 0..23); chunk = 1 KB where
// lane l=q*16+r holds 16 B = bf16 values W1[k = kg*32+q*8+j][n = h*16+r], j=0..7.
// A wave's MFMA B-fragment load is then ONE coalesced global_load_dwordx4.
__global__ __launch_bounds__(64) void prep_kernel(const float* __restrict__ W1,
                                                  short* __restrict__ W1T) {
    const int bid = blockIdx.x;                 // 768 chunks
    const int h = bid / 24, kg = bid % 24;
    const int lane = threadIdx.x & 63, q = lane >> 4, r = lane & 15;
    float f[8];
#pragma unroll
    for (int j = 0; j < 8; j++)
        f[j] = W1[(size_t)(kg * 32 + q * 8 + j) * HID + h * 16 + r];
    uint u[4];
#pragma unroll
    for (int i = 0; i < 4; i++)
        u[i] = ((uint)(unsigned short)f2bf_rne(f[2 * i + 1]) << 16) |
               (uint)(unsigned short)f2bf_rne(f[2 * i]);
    uint* dst = (uint*)(W1T + (size_t)bid * 512) + lane * 4;
    dst[0] = u[0]; dst[1] = u[1]; dst[2] = u[2]; dst[3] = u[3];
}

// ---------- MLP: block = 128M x 512N (full N), 8 waves (2M x 4N, 64x128 each).
// BK=64, 12 steps. A: R7's proven DMA staging (full-cache-line sources, XOR chunk
// swizzle both sides, 2x32KB ring = 64 KB LDS). B: NO LDS — fragment-linear W1T is
// read straight to registers with coalesced global_load_dwordx4 (786 KB, L1/L2-
// resident; removes 201 MB = 2/3 of all DMA-staged bytes, the empirical ~21.6
// KB/us/CU delivery law's dominant term). All vmem is manually counted (asm loads +
// asm vmcnt; compiler-counted loads would drain the A prefetch): per iter
// {vmcnt(4) A(t) ready; barrier; issue 16 B-loads; ds_read+pack A; vmcnt(8) ->
// MFMA kk0; vmcnt(0) -> MFMA kk1; barrier; stage A(t+2)}. sched_barrier after
// every wait (rule #18).
__global__ __launch_bounds__(512, 2) void mlp_kernel(const float* __restrict__ A,
                                                     const short* __restrict__ BT,
                                                     const float* __restrict__ b1,
                                                     const float* __restrict__ W2,
                                                     float* __restrict__ logits) {
    extern __shared__ char smem[];
    const int tid = threadIdx.x, wave = tid >> 6, lane = tid & 63;
    const int q = lane >> 4, r = lane & 15;
    const int wr = wave >> 2, wc = wave & 3;     // 2x4 wave grid
    const int m0 = blockIdx.x * 128;
    const int s7 = r & 7;

    char* rng0 = smem;                 // A ring buf 0: [128 rows][64 f32] = 32 KB
    char* rng1 = smem + 32768;         // A ring buf 1

    // ---- A DMA descriptors (R7-verbatim). 32 instrs of 1KB (4 rows x 256B);
    // wave w -> i=w*4+j. lane l: row = i*4 + (l>>4); LDS chunk kc_lds = l&15 holds
    // global chunk kc_glob = kc_lds ^ (row&7); dest = i*1024 + l*16 (linear).
    const float* aSrc[4];
    int aD[4];
#pragma unroll
    for (int j = 0; j < 4; j++) {
        int i = wave * 4 + j;
        int row = i * 4 + (lane >> 4);
        int kc = (lane & 15) ^ (row & 7);
        aSrc[j] = A + (size_t)(m0 + row) * DIM + kc * 4;
        aD[j] = i * 1024;
    }
    // ---- A frag-read offsets (swizzled; row&7 == r&7 for all our rows) ----
    int aOff[2][2];
#pragma unroll
    for (int kk = 0; kk < 2; kk++)
#pragma unroll
        for (int c = 0; c < 2; c++)
            aOff[kk][c] = (wr * 64 + r) * 256 + (((kk * 8 + q * 2 + c) ^ s7) * 16);

    float4v acc[4][8] = {};

    auto stageA = [&](int t, char* rb) {        // 4 DMA instrs / wave
        const int ko = t * 64;                  // float offset
#pragma unroll
        for (int j = 0; j < 4; j++) gl2lds16(aSrc[j] + ko, rb + aD[j]);
    };

    auto iter = [&](const char* ab, int t, char* sb, bool doStage) {
        asm volatile("s_waitcnt vmcnt(4)" ::: "memory");   // A(t) landed (mine)
        __builtin_amdgcn_s_barrier();                       // everyone's landed
        __builtin_amdgcn_sched_barrier(0);
        // B fragment loads: 16 coalesced dwordx4 straight from L1/L2 to regs
        FragU bFu[2][8];
#pragma unroll
        for (int kk = 0; kk < 2; kk++)
#pragma unroll
            for (int nf = 0; nf < 8; nf++) {
                const short* p = BT + (((size_t)((wc * 8 + nf) * 24 + t * 2 + kk)) << 9)
                               + lane * 8;
                asm volatile("global_load_dwordx4 %0, %1, off"
                             : "=v"(bFu[kk][nf].i4) : "v"(p) : "memory");
            }
        // A fragments: ds_read + bf16 pack (compiler inserts lgkm waits)
        FragU aFu[2][4];
#pragma unroll
        for (int kk = 0; kk < 2; kk++)
#pragma unroll
            for (int mf = 0; mf < 4; mf++) {
                float4v f0 = *(const float4v*)(ab + aOff[kk][0] + mf * 4096);
                float4v f1 = *(const float4v*)(ab + aOff[kk][1] + mf * 4096);
                aFu[kk][mf].u[0] = pack_bf2(f0[0], f0[1]);
                aFu[kk][mf].u[1] = pack_bf2(f0[2], f0[3]);
                aFu[kk][mf].u[2] = pack_bf2(f1[0], f1[1]);
                aFu[kk][mf].u[3] = pack_bf2(f1[2], f1[3]);
            }
        asm volatile("s_waitcnt vmcnt(8)" ::: "memory");   // B kk0 (8 newest = kk1 remain)
        __builtin_amdgcn_sched_barrier(0);
#pragma unroll
        for (int mf = 0; mf < 4; mf++)
#pragma unroll
            for (int nf = 0; nf < 8; nf++)
                acc[mf][nf] = __builtin_amdgcn_mfma_f32_16x16x32_bf16(
                    aFu[0][mf].s, bFu[0][nf].s, acc[mf][nf], 0, 0, 0);
        asm volatile("s_waitcnt vmcnt(0)" ::: "memory");   // B kk1 landed
        __builtin_amdgcn_sched_barrier(0);
#pragma unroll
        for (int mf = 0; mf < 4; mf++)
#pragma unroll
            for (int nf = 0; nf < 8; nf++)
                acc[mf][nf] = __builtin_amdgcn_mfma_f32_16x16x32_bf16(
                    aFu[1][mf].s, bFu[1][nf].s, acc[mf][nf], 0, 0, 0);
        __builtin_amdgcn_s_barrier();                       // all waves' LDS reads done
        if (doStage) stageA(t + 2, sb);                     // overwrite the buf just read
    };

    // prologue: fill ring (8 outstanding A-DMA / wave)
    stageA(0, rng0);
    stageA(1, rng1);
    // t = 0..9 stage t+2; 10,11 drain
    for (int tb = 0; tb < 10; tb += 2) {
        iter(rng0, tb, rng0, true);
        iter(rng1, tb + 1, rng1, true);
    }
    iter(rng0, 10, rng0, false);
    iter(rng1, 11, rng1, false);

    // epilogue: h = relu(acc + b1); partial over this wave's 128 cols
    float b1v[8], w2v[8];
#pragma unroll
    for (int nf = 0; nf < 8; nf++) {
        int gc = wc * 128 + nf * 16 + r;
        b1v[nf] = b1[gc];
        w2v[nf] = W2[gc];
    }
    __syncthreads();
    float* red = (float*)smem;   // [4 colgroups][128 rows] fp32 = 2 KB
#pragma unroll
    for (int mf = 0; mf < 4; mf++)
#pragma unroll
        for (int v = 0; v < 4; v++) {
            float pp = 0.f;
#pragma unroll
            for (int nf = 0; nf < 8; nf++) {
                float hh = acc[mf][nf][v] + b1v[nf];
                hh = hh > 0.f ? hh : 0.f;
                pp += hh * w2v[nf];
            }
#pragma unroll
            for (int off = 1; off < 16; off <<= 1) pp += __shfl_xor(pp, off, 64);
            if (r == 0) red[wc * 128 + wr * 64 + mf * 16 + q * 4 + v] = pp;
        }
    __syncthreads();
    if (tid < 128) {
        logits[m0 + tid] = red[tid] + red[128 + tid] + red[256 + tid] + red[384 + tid];
    }
}

// ---------- boundary: logits -> hard bits, per-batch scan -> segment starts ----------
__global__ __launch_bounds__(1024) void boundary_kernel(const float* __restrict__ logits,
                                                        const float* __restrict__ b2p,
                                                        const float* __restrict__ noise,
                                                        int* __restrict__ starts,   // [BATCH][SEQ+1]
                                                        int* __restrict__ nseg,     // [BATCH]
                                                        int* __restrict__ nbcount) {// [BATCH]
    const int b = blockIdx.x, tid = threadIdx.x;
    const int base = tid * 4;
    const float b2 = b2p[0];
    int h[4], c = 0;
#pragma unroll
    for (int j = 0; j < 4; j++) {
        int l = base + j;
        float u = noise[b * SEQ + l];
        float lg = logits[b * SEQ + l] + b2 + logf(u) - log1pf(-u);
        h[j] = (lg > 0.f) ? 1 : 0;
        c += h[j];
    }
    const int lane = tid & 63, wid = tid >> 6;
    int inc = c;
    for (int off = 1; off < 64; off <<= 1) {
        int t = __shfl_up(inc, off, 64);
        if (lane >= off) inc += t;
    }
    __shared__ int wtot[16], woff[16], extra[2];
    if (lane == 63) wtot[wid] = inc;
    if (tid == 1023) extra[0] = h[3];
    __syncthreads();
    if (tid == 0) {
        int s = 0;
        for (int i = 0; i < 16; i++) { woff[i] = s; s += wtot[i]; }
        extra[1] = s;
    }
    __syncthreads();
    int run = (inc - c) + woff[wid];       // exclusive prefix of hard bits
#pragma unroll
    for (int j = 0; j < 4; j++) {
        int l = base + j;
        if (h[j]) {
            run++;
            if (l < SEQ - 1) starts[b * (SEQ + 1) + run] = l + 1;
        }
    }
    if (tid == 0) {
        int total = extra[1];
        int ns = total + (extra[0] ? 0 : 1);
        starts[b * (SEQ + 1)] = 0;
        starts[b * (SEQ + 1) + ns] = SEQ;
        nseg[b] = ns;
        nbcount[b] = total;
    }
}

// ---------- pool: 4 waves/block, one wave per slot; 2-way row unroll; NT stores ----------
__global__ __launch_bounds__(256) void pool_kernel(const float* __restrict__ hidden,
                                                   const int* __restrict__ starts,
                                                   const int* __restrict__ nseg,
                                                   float* __restrict__ out) {
    const int wid = threadIdx.x >> 6, lane = threadIdx.x & 63;
    const int s = blockIdx.x * 4 + wid, b = blockIdx.y;
    float* orow = out + (size_t)(b * SEQ + s) * DIM;
    float4v a0 = {0.f, 0.f, 0.f, 0.f}, a1 = a0, a2 = a0;
    const int ns = nseg[b];
    if (s < ns) {
        const int st = starts[b * (SEQ + 1) + s];
        const int en = starts[b * (SEQ + 1) + s + 1];
        float4v c0 = a0, c1 = a0, c2 = a0;
        const float* hbase = hidden + (size_t)(b * SEQ) * DIM;
        int row = st;
        for (; row + 2 <= en; row += 2) {
            const float* h0 = hbase + (size_t)row * DIM;
            const float* h1 = h0 + DIM;
            a0 += *(const float4v*)(h0 + lane * 4);
            a1 += *(const float4v*)(h0 + (lane + 64) * 4);
            a2 += *(const float4v*)(h0 + (lane + 128) * 4);
            c0 += *(const float4v*)(h1 + lane * 4);
            c1 += *(const float4v*)(h1 + (lane + 64) * 4);
            c2 += *(const float4v*)(h1 + (lane + 128) * 4);
        }
        if (row < en) {
            const float* h0 = hbase + (size_t)row * DIM;
            a0 += *(const float4v*)(h0 + lane * 4);
            a1 += *(const float4v*)(h0 + (lane + 64) * 4);
            a2 += *(const float4v*)(h0 + (lane + 128) * 4);
        }
        a0 += c0; a1 += c1; a2 += c2;
        const float invc = 1.f / (float)(en - st);
        a0 *= invc; a1 *= invc; a2 *= invc;
    }
    __builtin_nontemporal_store(a0, (float4v*)(orow + lane * 4));
    __builtin_nontemporal_store(a1, (float4v*)(orow + (lane + 64) * 4));
    __builtin_nontemporal_store(a2, (float4v*)(orow + (lane + 128) * 4));
}

// ---------- finalize: loss / num_boundaries / total_positions ----------
__global__ void finalize_kernel(const int* __restrict__ nbcount, float* __restrict__ tail) {
    int nb = 0;
    for (int i = 0; i < BATCH; i++) nb += nbcount[i];
    float ratio = (float)nb / (float)M_TOK;
    float d = fabsf(ratio - 0.25f) - 0.05f;    // PRIOR + 0.05 = 0.25, margin 0.05
    tail[0] = d > 0.f ? d : 0.f;
    tail[1] = (float)nb;
    tail[2] = (float)M_TOK;
}

// ---------- launch ----------
#define MLP_LDS 65536
extern "C" void kernel_launch(void* const* d_in, const int* in_sizes, int n_in,
                              void* d_out, int out_size, void* d_ws, size_t ws_size,
                              hipStream_t stream) {
    const float* hidden = (const float*)d_in[0];
    const float* W1     = (const float*)d_in[1];
    const float* b1     = (const float*)d_in[2];
    const float* W2     = (const float*)d_in[3];
    const float* b2     = (const float*)d_in[4];
    const float* noise  = (const float*)d_in[5];

    char* ws = (char*)d_ws;
    short* W1T    = (short*)(ws);                    // 786432 B (fragment-linear)
    float* logits = (float*)(ws + 786432);           // 131072 B
    int*   starts = (int*)(ws + 917504);             // 131104 B
    int*   nseg   = (int*)(ws + 917504 + 131104);    // 32 B
    int*   nbcount = nseg + 8;                       // 32 B
    float* out    = (float*)d_out;

    static bool s_mlp_attr = false;
    if (!s_mlp_attr) {
        hipFuncSetAttribute(reinterpret_cast<const void*>(mlp_kernel),
                            hipFuncAttributeMaxDynamicSharedMemorySize, MLP_LDS);
        s_mlp_attr = true;
    }

    prep_kernel<<<768, 64, 0, stream>>>(W1, W1T);
    mlp_kernel<<<M_TOK / 128, 512, MLP_LDS, stream>>>(hidden, W1T, b1, W2, logits);
    boundary_kernel<<<BATCH, 1024, 0, stream>>>(logits, b2, noise, starts, nseg, nbcount);
    pool_kernel<<<dim3(SEQ / 4, BATCH), 256, 0, stream>>>(hidden, starts, nseg, out);
    finalize_kernel<<<1, 1, 0, stream>>>(nbcount, out + (size_t)M_TOK * DIM);
}